// Round 6
// baseline (25912.091 us; speedup 1.0000x reference)
//
#include <hip/hip_runtime.h>

// LIF benchmark: xs = einsum('tbf,gf->tbg', S, W)  (fp32 GEMM, A=S [T*B,512], B=W [512,512], NT)
// then sequential scan over T with per-neuron (v,i) state and heaviside threshold.
// Outputs: [z_final, z_final, v_final, i_final], each [128,512] fp32.
//
// R11 (session R6): post-mortem facts driving this round:
//   - R9/R10 (16x16 micro): NO spill (WRITE_SIZE flat, conflicts 0) but VALU
//     busy-cycles DOUBLED (581->1146us for the same 437us of FMA): 256 acc
//     forced AGPR shuttling (v_accvgpr_read/write around FMAs). RULE: acc
//     must stay <=128 regs. 16x16 geometry abandoned.
//   - R7 measured occupancy 21% at LDS=50176 => only 2 blocks/CU resident
//     (the allocatable LDS pool behaves like ~128KB, not 160KB). R7's 25%
//     VALU-idle is stall that 2 lockstep blocks can't hide.
// This round: R7's exact 8x16 micro-tile and dbuf pipeline, but KC 16->8:
//   LDS 50176 -> 25088 B => 4 blocks/CU (16 waves). __launch_bounds__(256,4)
//   pins VGPR <=128 (compiler used ~104 at KC=16). Prefetch lead still one
//   full tile (2048cy >= HBM latency). Staging for KC=8: A = 1 float4/thread
//   (row tid>>1, k (tid&1)*4), B = 2 float4; write banks 2 lanes/bank (free).
//   FMA expression + ascending-k order verbatim R7 -> absmax 0.0.
// Scan: DEPTH 32->64 (R3's scan, correctness-proven in the R3 run): scan is
//   outstanding-load-limited at 4 waves/CU; 2x ring depth = 2x bytes in flight.
// Tripwires: WRITE_SIZE must stay ~262144 KB; VGPR <= ~110; occupancy ~40%.

#define T_DIM 1024
#define B_DIM 128
#define F_DIM 512
#define NB (B_DIM * F_DIM)  // 65536 neurons

// ---------------- GEMM: C[m][n] = sum_k A[m][k] * W[n][k] ----------------
// Block tile 128m x 256n, 256 threads, 8x16 micro-tile, KC=8, double-buffered.
#define TM 128
#define TN 256
#define KC 8
#define LDA_S 132            // As row pad (132%32==4)
#define LDB_S 260            // Bs row pad (260%32==4)
#define A_SZ (KC * LDA_S)    // 1056 floats per buffer
#define B_SZ (KC * LDB_S)    // 2080 floats per buffer

__global__ __launch_bounds__(256, 4)
void gemm_kernel(const float* __restrict__ A, const float* __restrict__ W,
                 float* __restrict__ C) {
    __shared__ float As[2 * A_SZ];  // [buf][k][m]
    __shared__ float Bs[2 * B_SZ];  // [buf][k][n]
    const int tid = threadIdx.x;
    const int m0 = blockIdx.x * TM;
    const int n0 = blockIdx.y * TN;
    const int tn4 = (tid & 15) * 4;  // b cols: tn4 + {0..3} + 64q, q=0..3
    const int tm4 = (tid >> 4) * 4;  // a rows: tm4 + {0..3} and +64
    const int sra = tid >> 1;        // A staging row 0..127
    const int srb = tid >> 1;        // B staging row 0..127 (+128p)
    const int sk = (tid & 1) * 4;    // staging k 0 or 4

    float acc[8][16];
    #pragma unroll
    for (int i = 0; i < 8; ++i)
        #pragma unroll
        for (int j = 0; j < 16; ++j) acc[i][j] = 0.f;

    // ---- prologue: stage tile k0=0 into buffer 0 ----
    {
        const float4 av = *(const float4*)(A + (size_t)(m0 + sra) * F_DIM + sk);
        float4 bv[2];
        #pragma unroll
        for (int p = 0; p < 2; ++p)
            bv[p] = *(const float4*)(W + (size_t)(n0 + srb + 128 * p) * F_DIM + sk);
        As[(sk + 0) * LDA_S + sra] = av.x;  As[(sk + 1) * LDA_S + sra] = av.y;
        As[(sk + 2) * LDA_S + sra] = av.z;  As[(sk + 3) * LDA_S + sra] = av.w;
        #pragma unroll
        for (int p = 0; p < 2; ++p) {
            const int r = srb + 128 * p;
            Bs[(sk + 0) * LDB_S + r] = bv[p].x;  Bs[(sk + 1) * LDB_S + r] = bv[p].y;
            Bs[(sk + 2) * LDB_S + r] = bv[p].z;  Bs[(sk + 3) * LDB_S + r] = bv[p].w;
        }
        __syncthreads();
    }

    int cur = 0;
    for (int k0 = 0; k0 < F_DIM; k0 += KC) {
        const bool more = (k0 + KC < F_DIM);
        // issue next tile's global loads first: one-tile (2048cy) lead time
        float4 av, bv[2];
        if (more) {
            av = *(const float4*)(A + (size_t)(m0 + sra) * F_DIM + (k0 + KC) + sk);
            #pragma unroll
            for (int p = 0; p < 2; ++p)
                bv[p] = *(const float4*)(W + (size_t)(n0 + srb + 128 * p) * F_DIM
                                           + (k0 + KC) + sk);
        }

        // ---- compute on buf[cur] ----
        const float* asb = As + cur * A_SZ;
        const float* bsb = Bs + cur * B_SZ;
        #pragma unroll
        for (int k = 0; k < KC; ++k) {
            const float4 a0 = *(const float4*)(asb + k * LDA_S + tm4);
            const float4 a1 = *(const float4*)(asb + k * LDA_S + tm4 + 64);
            const float4 b0 = *(const float4*)(bsb + k * LDB_S + tn4);
            const float4 b1 = *(const float4*)(bsb + k * LDB_S + tn4 + 64);
            const float4 b2 = *(const float4*)(bsb + k * LDB_S + tn4 + 128);
            const float4 b3 = *(const float4*)(bsb + k * LDB_S + tn4 + 192);
            const float a[8] = {a0.x, a0.y, a0.z, a0.w, a1.x, a1.y, a1.z, a1.w};
            const float b[16] = {b0.x, b0.y, b0.z, b0.w, b1.x, b1.y, b1.z, b1.w,
                                 b2.x, b2.y, b2.z, b2.w, b3.x, b3.y, b3.z, b3.w};
            #pragma unroll
            for (int i = 0; i < 8; ++i)
                #pragma unroll
                for (int j = 0; j < 16; ++j)
                    acc[i][j] += a[i] * b[j];
        }

        // ---- stage next tile into buf[cur^1] ----
        if (more) {
            float* asn = As + (cur ^ 1) * A_SZ;
            float* bsn = Bs + (cur ^ 1) * B_SZ;
            asn[(sk + 0) * LDA_S + sra] = av.x;  asn[(sk + 1) * LDA_S + sra] = av.y;
            asn[(sk + 2) * LDA_S + sra] = av.z;  asn[(sk + 3) * LDA_S + sra] = av.w;
            #pragma unroll
            for (int p = 0; p < 2; ++p) {
                const int r = srb + 128 * p;
                bsn[(sk + 0) * LDB_S + r] = bv[p].x;  bsn[(sk + 1) * LDB_S + r] = bv[p].y;
                bsn[(sk + 2) * LDB_S + r] = bv[p].z;  bsn[(sk + 3) * LDB_S + r] = bv[p].w;
            }
            __syncthreads();
            cur ^= 1;
        }
    }

    #pragma unroll
    for (int i = 0; i < 8; ++i) {
        const int m = m0 + ((i < 4) ? (tm4 + i) : (tm4 + 60 + i));  // tm4+64+(i-4)
        #pragma unroll
        for (int q = 0; q < 4; ++q) {
            const float4 c = make_float4(acc[i][4 * q + 0], acc[i][4 * q + 1],
                                         acc[i][4 * q + 2], acc[i][4 * q + 3]);
            *(float4*)(C + (size_t)m * F_DIM + n0 + tn4 + 64 * q) = c;
        }
    }
}

// ---------------- sequential LIF scan over a chunk of Tc steps ----------------
// R3/R5 structure, ring depth 64 (correctness-proven in the R3 run).
// Explicit _rn intrinsics: forbid fma contraction (matches reference rounding).
#define DEPTH 64

__global__ __launch_bounds__(256)
void scan_kernel(const float* __restrict__ xs, float* __restrict__ vi,
                 float* __restrict__ out, int Tc, int first, int last) {
    const int j = blockIdx.x * 256 + threadIdx.x;  // neuron id, 0..NB-1
    float v, cur;
    if (first) { v = 0.f; cur = 0.f; }
    else       { v = vi[j]; cur = vi[NB + j]; }
    float z = 0.f;
    const float* pj = xs + j;

    if (Tc >= DEPTH && (Tc % DEPTH) == 0) {
        float buf[DEPTH];
        #pragma unroll
        for (int d = 0; d < DEPTH; ++d) buf[d] = pj[(size_t)d * NB];
        for (int tt = 0; tt < Tc; tt += DEPTH) {
            #pragma unroll
            for (int d = 0; d < DEPTH; ++d) {
                const float x = buf[d];
                int tn = tt + DEPTH + d;
                tn = (tn < Tc) ? tn : 0;          // clamped dead prefetch at tail
                buf[d] = pj[(size_t)tn * NB];
                const float vd = __fadd_rn(v, __fmul_rn(0.1f, __fsub_rn(cur, v)));
                const float id = __fadd_rn(cur, __fmul_rn(-0.2f, cur));
                const bool sp = vd > 1.0f;
                z = sp ? 1.f : 0.f;
                v = sp ? 0.f : vd;
                cur = __fadd_rn(id, x);
            }
        }
    } else {
        for (int t = 0; t < Tc; ++t) {
            const float x = pj[(size_t)t * NB];
            const float vd = __fadd_rn(v, __fmul_rn(0.1f, __fsub_rn(cur, v)));
            const float id = __fadd_rn(cur, __fmul_rn(-0.2f, cur));
            const bool sp = vd > 1.0f;
            z = sp ? 1.f : 0.f;
            v = sp ? 0.f : vd;
            cur = __fadd_rn(id, x);
        }
    }

    if (last) {
        out[j]           = z;
        out[NB + j]      = z;
        out[2 * NB + j]  = v;
        out[3 * NB + j]  = cur;
    } else {
        vi[j]      = v;
        vi[NB + j] = cur;
    }
}

extern "C" void kernel_launch(void* const* d_in, const int* in_sizes, int n_in,
                              void* d_out, int out_size, void* d_ws, size_t ws_size,
                              hipStream_t stream) {
    const float* S = (const float*)d_in[0];  // [T,B,F] fp32
    const float* W = (const float*)d_in[1];  // [F,F] fp32
    float* out = (float*)d_out;
    float* vi = (float*)d_ws;        // 2*NB floats of state
    float* xs = vi + 2 * NB;         // chunk buffer [Tc, NB]
    // pick largest power-of-two chunk Tc whose xs buffer fits the workspace
    const size_t avail_f = (ws_size / 4 > (size_t)(2 * NB)) ? ws_size / 4 - 2 * NB : 0;
    int Tc = T_DIM;
    while (Tc > 1 && (size_t)Tc * NB > avail_f) Tc >>= 1;
    const int nc = T_DIM / Tc;
    for (int c = 0; c < nc; ++c) {
        const int M = Tc * B_DIM;
        dim3 grid(M / TM, F_DIM / TN);
        gemm_kernel<<<grid, 256, 0, stream>>>(S + (size_t)c * Tc * NB, W, xs);
        scan_kernel<<<NB / 256, 256, 0, stream>>>(xs, vi, out, Tc,
                                                  (c == 0) ? 1 : 0,
                                                  (c == nc - 1) ? 1 : 0);
    }
}

// Round 8
// 1099.564 us; speedup vs baseline: 23.5658x; 23.5658x over previous
//
#include <hip/hip_runtime.h>

// LIF benchmark: xs = einsum('tbf,gf->tbg', S, W)  (fp32 GEMM, A=S [T*B,512], B=W [512,512], NT)
// then sequential scan over T with per-neuron (v,i) state and heaviside threshold.
// Outputs: [z_final, z_final, v_final, i_final], each [128,512] fp32.
//
// R13 (session R8): RESUBMIT of R12 unchanged -- R12's bench died to the
// broker/container failure (no pytest/absmax/rocprof), same infra signature
// as R4. Kernel audit found no OOB/hang/workspace fault. Keeping the
// experiment identical so the counters answer the original question.
//
// Facts bank:
//   - R6: __launch_bounds__(256,4) caps unified regs at 128/wave; kernel needs
//     ~232 -> total spill (WRITE 60GB, VALU 1.8%). NEVER bound above 2 waves/EU.
//   - Occupancy on this geometry is REGISTER-limited (232/wave -> 2 waves/SIMD);
//     LDS shrink cannot raise it. Occupancy lever is dead.
//   - R2 (best gemm, 780us): LDS pipe saturated: per k per CU = 576cy reads +
//     ~70cy writes vs 512cy VALU -> VALUBusy model 79% ~= measured 74.5%.
//   - R3: named B ring buffers across the FMA body -> acc evicted, 8GB scratch.
//   - Scan DEPTH=64 measured ~110-120us (R3/R6 runs) vs ~230 at DEPTH=32.
// This round: remove B from LDS entirely (it is 4/6 reads + 2/3 writes):
//   - transpose W once (R3's proven kernel) -> Wt[k][n].
//   - k-loop loads B fragments DIRECTLY from Wt, immediate consumption, no
//     named buffers; #pragma unroll 4 bounds in-flight loads (~64 regs).
//     Wt row k per n-panel = 1KB, L1-resident; W total 1MB, L2-resident.
//   - LDS keeps A only (KC=16 dbuf, staging verbatim from the 780us kernel):
//     LDS pipe ~220cy/k << 512cy VALU -> VALU binding.
//   - b bitwise equal to W[n][k]; FMA expr + ascending-k order verbatim
//     -> absmax 0.0.
// Tripwire: WRITE_SIZE must stay ~262144 KB (else spill -> revert to R2+scan64).

#define T_DIM 1024
#define B_DIM 128
#define F_DIM 512
#define NB (B_DIM * F_DIM)  // 65536 neurons

// ---------------- W transpose: Wt[k][n] = W[n][k] ----------------
// Proven in the R3 run (absmax 0.0 end-to-end through Wt).
__global__ __launch_bounds__(256)
void transpose_kernel(const float* __restrict__ W, float* __restrict__ Wt) {
    __shared__ float t[64][65];
    const int bx = blockIdx.x, by = blockIdx.y;
    const int c = threadIdx.x & 63;
    const int r0 = (threadIdx.x >> 6) * 16;
    #pragma unroll
    for (int i = 0; i < 16; ++i) {
        const int row = r0 + i;
        t[row][c] = W[(size_t)(by * 64 + row) * F_DIM + bx * 64 + c];
    }
    __syncthreads();
    #pragma unroll
    for (int i = 0; i < 16; ++i) {
        const int row = r0 + i;
        Wt[(size_t)(bx * 64 + row) * F_DIM + by * 64 + c] = t[c][row];
    }
}

// ---------------- GEMM: C[m][n] = sum_k A[m][k] * Wt[k][n] ----------------
// Block tile 128m x 256n, 256 threads, 8x16 micro-tile, KC=16.
// A double-buffered in LDS (verbatim 780us-kernel staging); B direct from Wt.
#define TM 128
#define TN 256
#define KC 16
#define LDA_S 132            // As row pad
#define A_SZ (KC * LDA_S)    // 2112 floats per buffer

__global__ __launch_bounds__(256, 2)
void gemm_kernel(const float* __restrict__ A, const float* __restrict__ Wt,
                 float* __restrict__ C) {
    __shared__ float As[2 * A_SZ];  // [buf][k][m]
    const int tid = threadIdx.x;
    const int m0 = blockIdx.x * TM;
    const int n0 = blockIdx.y * TN;
    const int tn4 = (tid & 15) * 4;  // b cols: tn4 + {0..3} + 64q, q=0..3
    const int tm4 = (tid >> 4) * 4;  // a rows: tm4 + {0..3} and +64
    const int srow = tid >> 2;       // A staging row 0..63 (+64)
    const int sk = (tid & 3) * 4;    // A staging k 0,4,8,12

    float acc[8][16];
    #pragma unroll
    for (int i = 0; i < 8; ++i)
        #pragma unroll
        for (int j = 0; j < 16; ++j) acc[i][j] = 0.f;

    const float* wbase = Wt + n0 + tn4;  // + k*F_DIM + 64q

    // ---- prologue: stage A tile k0=0 into buffer 0 ----
    {
        float4 av[2];
        #pragma unroll
        for (int p = 0; p < 2; ++p)
            av[p] = *(const float4*)(A + (size_t)(m0 + srow + 64 * p) * F_DIM + sk);
        #pragma unroll
        for (int p = 0; p < 2; ++p) {
            const int r = srow + 64 * p;
            As[(sk + 0) * LDA_S + r] = av[p].x;  As[(sk + 1) * LDA_S + r] = av[p].y;
            As[(sk + 2) * LDA_S + r] = av[p].z;  As[(sk + 3) * LDA_S + r] = av[p].w;
        }
        __syncthreads();
    }

    int cur = 0;
    for (int k0 = 0; k0 < F_DIM; k0 += KC) {
        const bool more = (k0 + KC < F_DIM);
        // next A-tile global loads first (one-tile lead; consumed at the stores)
        float4 av[2];
        if (more) {
            #pragma unroll
            for (int p = 0; p < 2; ++p)
                av[p] = *(const float4*)(A + (size_t)(m0 + srow + 64 * p) * F_DIM
                                           + (k0 + KC) + sk);
        }

        // ---- compute on buf[cur]; B straight from global (L1/L2-hot) ----
        const float* asb = As + cur * A_SZ;
        const float* wk0 = wbase + (size_t)k0 * F_DIM;
        #pragma unroll 4
        for (int k = 0; k < KC; ++k) {
            const float4 a0 = *(const float4*)(asb + k * LDA_S + tm4);
            const float4 a1 = *(const float4*)(asb + k * LDA_S + tm4 + 64);
            const float* wk = wk0 + (size_t)k * F_DIM;
            const float4 b0 = *(const float4*)(wk);
            const float4 b1 = *(const float4*)(wk + 64);
            const float4 b2 = *(const float4*)(wk + 128);
            const float4 b3 = *(const float4*)(wk + 192);
            const float a[8] = {a0.x, a0.y, a0.z, a0.w, a1.x, a1.y, a1.z, a1.w};
            const float b[16] = {b0.x, b0.y, b0.z, b0.w, b1.x, b1.y, b1.z, b1.w,
                                 b2.x, b2.y, b2.z, b2.w, b3.x, b3.y, b3.z, b3.w};
            #pragma unroll
            for (int i = 0; i < 8; ++i)
                #pragma unroll
                for (int j = 0; j < 16; ++j)
                    acc[i][j] += a[i] * b[j];
        }

        // ---- stage next A tile into buf[cur^1] ----
        if (more) {
            float* asn = As + (cur ^ 1) * A_SZ;
            #pragma unroll
            for (int p = 0; p < 2; ++p) {
                const int r = srow + 64 * p;
                asn[(sk + 0) * LDA_S + r] = av[p].x;  asn[(sk + 1) * LDA_S + r] = av[p].y;
                asn[(sk + 2) * LDA_S + r] = av[p].z;  asn[(sk + 3) * LDA_S + r] = av[p].w;
            }
            __syncthreads();
            cur ^= 1;
        }
    }

    #pragma unroll
    for (int i = 0; i < 8; ++i) {
        const int m = m0 + ((i < 4) ? (tm4 + i) : (tm4 + 60 + i));  // tm4+64+(i-4)
        #pragma unroll
        for (int q = 0; q < 4; ++q) {
            const float4 c = make_float4(acc[i][4 * q + 0], acc[i][4 * q + 1],
                                         acc[i][4 * q + 2], acc[i][4 * q + 3]);
            *(float4*)(C + (size_t)m * F_DIM + n0 + tn4 + 64 * q) = c;
        }
    }
}

// ---------------- sequential LIF scan over a chunk of Tc steps ----------------
// R3/R6-proven scan, DEPTH=64 (measured ~2x faster than DEPTH=32).
// Explicit _rn intrinsics: forbid fma contraction (matches reference rounding).
#define DEPTH 64

__global__ __launch_bounds__(256)
void scan_kernel(const float* __restrict__ xs, float* __restrict__ vi,
                 float* __restrict__ out, int Tc, int first, int last) {
    const int j = blockIdx.x * 256 + threadIdx.x;  // neuron id, 0..NB-1
    float v, cur;
    if (first) { v = 0.f; cur = 0.f; }
    else       { v = vi[j]; cur = vi[NB + j]; }
    float z = 0.f;
    const float* pj = xs + j;

    if (Tc >= DEPTH && (Tc % DEPTH) == 0) {
        float buf[DEPTH];
        #pragma unroll
        for (int d = 0; d < DEPTH; ++d) buf[d] = pj[(size_t)d * NB];
        for (int tt = 0; tt < Tc; tt += DEPTH) {
            #pragma unroll
            for (int d = 0; d < DEPTH; ++d) {
                const float x = buf[d];
                int tn = tt + DEPTH + d;
                tn = (tn < Tc) ? tn : 0;          // clamped dead prefetch at tail
                buf[d] = pj[(size_t)tn * NB];
                const float vd = __fadd_rn(v, __fmul_rn(0.1f, __fsub_rn(cur, v)));
                const float id = __fadd_rn(cur, __fmul_rn(-0.2f, cur));
                const bool sp = vd > 1.0f;
                z = sp ? 1.f : 0.f;
                v = sp ? 0.f : vd;
                cur = __fadd_rn(id, x);
            }
        }
    } else {
        for (int t = 0; t < Tc; ++t) {
            const float x = pj[(size_t)t * NB];
            const float vd = __fadd_rn(v, __fmul_rn(0.1f, __fsub_rn(cur, v)));
            const float id = __fadd_rn(cur, __fmul_rn(-0.2f, cur));
            const bool sp = vd > 1.0f;
            z = sp ? 1.f : 0.f;
            v = sp ? 0.f : vd;
            cur = __fadd_rn(id, x);
        }
    }

    if (last) {
        out[j]           = z;
        out[NB + j]      = z;
        out[2 * NB + j]  = v;
        out[3 * NB + j]  = cur;
    } else {
        vi[j]      = v;
        vi[NB + j] = cur;
    }
}

extern "C" void kernel_launch(void* const* d_in, const int* in_sizes, int n_in,
                              void* d_out, int out_size, void* d_ws, size_t ws_size,
                              hipStream_t stream) {
    const float* S = (const float*)d_in[0];  // [T,B,F] fp32
    const float* W = (const float*)d_in[1];  // [F,F] fp32
    float* out = (float*)d_out;
    float* vi = (float*)d_ws;                  // 2*NB floats of state
    float* Wt = vi + 2 * NB;                   // 512*512 transposed W
    float* xs = Wt + (size_t)F_DIM * F_DIM;    // chunk buffer [Tc, NB]
    // pick largest power-of-two chunk Tc whose xs buffer fits the workspace
    const size_t used = (size_t)2 * NB + (size_t)F_DIM * F_DIM;
    const size_t avail_f = (ws_size / 4 > used) ? ws_size / 4 - used : 0;
    int Tc = T_DIM;
    while (Tc > 1 && (size_t)Tc * NB > avail_f) Tc >>= 1;
    const int nc = T_DIM / Tc;

    transpose_kernel<<<dim3(8, 8), 256, 0, stream>>>(W, Wt);

    for (int c = 0; c < nc; ++c) {
        const int M = Tc * B_DIM;
        dim3 grid(M / TM, F_DIM / TN);
        gemm_kernel<<<grid, 256, 0, stream>>>(S + (size_t)c * Tc * NB, Wt, xs);
        scan_kernel<<<NB / 256, 256, 0, stream>>>(xs, vi, out, Tc,
                                                  (c == 0) ? 1 : 0,
                                                  (c == nc - 1) ? 1 : 0);
    }
}

// Round 9
// 1027.669 us; speedup vs baseline: 25.2144x; 1.0700x over previous
//
#include <hip/hip_runtime.h>

// LIF benchmark: xs = einsum('tbf,gf->tbg', S, W)  (fp32 GEMM, A=S [T*B,512], B=W [512,512], NT)
// then sequential scan over T with per-neuron (v,i) state and heaviside threshold.
// Outputs: [z_final, z_final, v_final, i_final], each [128,512] fp32.
//
// R14 (session R9): COMPOSE the session's proven-best pieces. Banking round.
//   - GEMM: verbatim R2/R7-kernel (780us, best of 8 attempts): 128x256 tile,
//     8x16 micro, KC=16 double-buffered LDS, conflict-free staging
//     (srow=tid>>2, sk=(tid&3)*4). Three experiments showed it's a local
//     optimum: R1 A-prefetch neutral; R3 B-in-regs -> acc spill (8GB scratch);
//     R8 B-from-global -> exposed VMEM latency (910us, VALUBusy 61.5%).
//   - Scan: DEPTH=64 ring (passed R3/R6/R8; ~60-70us faster than DEPTH=32 by
//     matched-run subtraction; 64 = vmcnt outstanding cap, deeper is useless).
//   - Transpose/Wt dropped (R8-only artifact).
// Facts bank (carried):
//   - acc must stay <=128 regs (16x16 micro -> AGPR shuttle, VALU-cycles 2x).
//   - NEVER __launch_bounds__ min-waves > 2 (reg cap 128 -> total spill).
//   - Occupancy is register-limited (~232/wave -> 2 blocks/CU); LDS shrink
//     cannot raise it (R6: 25KB LDS still 2 blocks by regs).
//   - GEMM LDS-pipe floor ~540us; measured 780; stall resists scheduling.
// Tripwires: gemm VALUBusy ~74 / WRITE_SIZE ~262144 KB; total ~950-990us.

#define T_DIM 1024
#define B_DIM 128
#define F_DIM 512
#define NB (B_DIM * F_DIM)  // 65536 neurons

// ---------------- GEMM: C[m][n] = sum_k A[m][k] * W[n][k] ----------------
// Block tile 128m x 256n, 256 threads, 8x16 micro-tile, KC=16, double-buffered.
#define TM 128
#define TN 256
#define KC 16
#define LDA_S 132            // As row pad (132%32==4)
#define LDB_S 260            // Bs row pad (260%32==4)
#define A_SZ (KC * LDA_S)    // 2112 floats per buffer
#define B_SZ (KC * LDB_S)    // 4160 floats per buffer

__global__ __launch_bounds__(256, 2)
void gemm_kernel(const float* __restrict__ A, const float* __restrict__ W,
                 float* __restrict__ C) {
    __shared__ float As[2 * A_SZ];  // [buf][k][m]
    __shared__ float Bs[2 * B_SZ];  // [buf][k][n]
    const int tid = threadIdx.x;
    const int m0 = blockIdx.x * TM;
    const int n0 = blockIdx.y * TN;
    const int tn4 = (tid & 15) * 4;  // b cols: tn4 + {0..3} + 64q, q=0..3
    const int tm4 = (tid >> 4) * 4;  // a rows: tm4 + {0..3} and +64
    const int srow = tid >> 2;       // staging row 0..63 (+64p)
    const int sk = (tid & 3) * 4;    // staging k 0,4,8,12

    float acc[8][16];
    #pragma unroll
    for (int i = 0; i < 8; ++i)
        #pragma unroll
        for (int j = 0; j < 16; ++j) acc[i][j] = 0.f;

    // ---- prologue: stage tile k0=0 into buffer 0 ----
    {
        float4 av[2], bv[4];
        #pragma unroll
        for (int p = 0; p < 2; ++p)
            av[p] = *(const float4*)(A + (size_t)(m0 + srow + 64 * p) * F_DIM + sk);
        #pragma unroll
        for (int p = 0; p < 4; ++p)
            bv[p] = *(const float4*)(W + (size_t)(n0 + srow + 64 * p) * F_DIM + sk);
        #pragma unroll
        for (int p = 0; p < 2; ++p) {
            const int r = srow + 64 * p;
            As[(sk + 0) * LDA_S + r] = av[p].x;  As[(sk + 1) * LDA_S + r] = av[p].y;
            As[(sk + 2) * LDA_S + r] = av[p].z;  As[(sk + 3) * LDA_S + r] = av[p].w;
        }
        #pragma unroll
        for (int p = 0; p < 4; ++p) {
            const int r = srow + 64 * p;
            Bs[(sk + 0) * LDB_S + r] = bv[p].x;  Bs[(sk + 1) * LDB_S + r] = bv[p].y;
            Bs[(sk + 2) * LDB_S + r] = bv[p].z;  Bs[(sk + 3) * LDB_S + r] = bv[p].w;
        }
        __syncthreads();
    }

    int cur = 0;
    for (int k0 = 0; k0 < F_DIM; k0 += KC) {
        const bool more = (k0 + KC < F_DIM);
        // issue next tile's global loads BEFORE compute: latency hides under it
        float4 av[2], bv[4];
        if (more) {
            #pragma unroll
            for (int p = 0; p < 2; ++p)
                av[p] = *(const float4*)(A + (size_t)(m0 + srow + 64 * p) * F_DIM
                                           + (k0 + KC) + sk);
            #pragma unroll
            for (int p = 0; p < 4; ++p)
                bv[p] = *(const float4*)(W + (size_t)(n0 + srow + 64 * p) * F_DIM
                                           + (k0 + KC) + sk);
        }

        // ---- compute on buf[cur] ----
        const float* asb = As + cur * A_SZ;
        const float* bsb = Bs + cur * B_SZ;
        #pragma unroll 4
        for (int k = 0; k < KC; ++k) {
            const float4 a0 = *(const float4*)(asb + k * LDA_S + tm4);
            const float4 a1 = *(const float4*)(asb + k * LDA_S + tm4 + 64);
            const float4 b0 = *(const float4*)(bsb + k * LDB_S + tn4);
            const float4 b1 = *(const float4*)(bsb + k * LDB_S + tn4 + 64);
            const float4 b2 = *(const float4*)(bsb + k * LDB_S + tn4 + 128);
            const float4 b3 = *(const float4*)(bsb + k * LDB_S + tn4 + 192);
            const float a[8] = {a0.x, a0.y, a0.z, a0.w, a1.x, a1.y, a1.z, a1.w};
            const float b[16] = {b0.x, b0.y, b0.z, b0.w, b1.x, b1.y, b1.z, b1.w,
                                 b2.x, b2.y, b2.z, b2.w, b3.x, b3.y, b3.z, b3.w};
            #pragma unroll
            for (int i = 0; i < 8; ++i)
                #pragma unroll
                for (int j = 0; j < 16; ++j)
                    acc[i][j] += a[i] * b[j];
        }

        // ---- stage next tile into buf[cur^1]; safe: everyone left it at the
        //      barrier ending tile t-1 ----
        if (more) {
            float* asn = As + (cur ^ 1) * A_SZ;
            float* bsn = Bs + (cur ^ 1) * B_SZ;
            #pragma unroll
            for (int p = 0; p < 2; ++p) {
                const int r = srow + 64 * p;
                asn[(sk + 0) * LDA_S + r] = av[p].x;  asn[(sk + 1) * LDA_S + r] = av[p].y;
                asn[(sk + 2) * LDA_S + r] = av[p].z;  asn[(sk + 3) * LDA_S + r] = av[p].w;
            }
            #pragma unroll
            for (int p = 0; p < 4; ++p) {
                const int r = srow + 64 * p;
                bsn[(sk + 0) * LDB_S + r] = bv[p].x;  bsn[(sk + 1) * LDB_S + r] = bv[p].y;
                bsn[(sk + 2) * LDB_S + r] = bv[p].z;  bsn[(sk + 3) * LDB_S + r] = bv[p].w;
            }
            __syncthreads();
            cur ^= 1;
        }
    }

    #pragma unroll
    for (int i = 0; i < 8; ++i) {
        const int m = m0 + ((i < 4) ? (tm4 + i) : (tm4 + 60 + i));  // tm4+64+(i-4)
        #pragma unroll
        for (int q = 0; q < 4; ++q) {
            const float4 c = make_float4(acc[i][4 * q + 0], acc[i][4 * q + 1],
                                         acc[i][4 * q + 2], acc[i][4 * q + 3]);
            *(float4*)(C + (size_t)m * F_DIM + n0 + tn4 + 64 * q) = c;
        }
    }
}

// ---------------- sequential LIF scan over a chunk of Tc steps ----------------
// DEPTH=64 ring (passed R3/R6/R8; 64 = per-wave outstanding-VMEM cap).
// Explicit _rn intrinsics: forbid fma contraction (matches reference rounding).
#define DEPTH 64

__global__ __launch_bounds__(256)
void scan_kernel(const float* __restrict__ xs, float* __restrict__ vi,
                 float* __restrict__ out, int Tc, int first, int last) {
    const int j = blockIdx.x * 256 + threadIdx.x;  // neuron id, 0..NB-1
    float v, cur;
    if (first) { v = 0.f; cur = 0.f; }
    else       { v = vi[j]; cur = vi[NB + j]; }
    float z = 0.f;
    const float* pj = xs + j;

    if (Tc >= DEPTH && (Tc % DEPTH) == 0) {
        float buf[DEPTH];
        #pragma unroll
        for (int d = 0; d < DEPTH; ++d) buf[d] = pj[(size_t)d * NB];
        for (int tt = 0; tt < Tc; tt += DEPTH) {
            #pragma unroll
            for (int d = 0; d < DEPTH; ++d) {
                const float x = buf[d];
                int tn = tt + DEPTH + d;
                tn = (tn < Tc) ? tn : 0;          // clamped dead prefetch at tail
                buf[d] = pj[(size_t)tn * NB];
                const float vd = __fadd_rn(v, __fmul_rn(0.1f, __fsub_rn(cur, v)));
                const float id = __fadd_rn(cur, __fmul_rn(-0.2f, cur));
                const bool sp = vd > 1.0f;
                z = sp ? 1.f : 0.f;
                v = sp ? 0.f : vd;
                cur = __fadd_rn(id, x);
            }
        }
    } else {
        for (int t = 0; t < Tc; ++t) {
            const float x = pj[(size_t)t * NB];
            const float vd = __fadd_rn(v, __fmul_rn(0.1f, __fsub_rn(cur, v)));
            const float id = __fadd_rn(cur, __fmul_rn(-0.2f, cur));
            const bool sp = vd > 1.0f;
            z = sp ? 1.f : 0.f;
            v = sp ? 0.f : vd;
            cur = __fadd_rn(id, x);
        }
    }

    if (last) {
        out[j]           = z;
        out[NB + j]      = z;
        out[2 * NB + j]  = v;
        out[3 * NB + j]  = cur;
    } else {
        vi[j]      = v;
        vi[NB + j] = cur;
    }
}

extern "C" void kernel_launch(void* const* d_in, const int* in_sizes, int n_in,
                              void* d_out, int out_size, void* d_ws, size_t ws_size,
                              hipStream_t stream) {
    const float* S = (const float*)d_in[0];  // [T,B,F] fp32
    const float* W = (const float*)d_in[1];  // [F,F] fp32
    float* out = (float*)d_out;
    float* vi = (float*)d_ws;        // 2*NB floats of state
    float* xs = vi + 2 * NB;         // chunk buffer [Tc, NB]
    // pick largest power-of-two chunk Tc whose xs buffer fits the workspace
    const size_t avail_f = (ws_size / 4 > (size_t)(2 * NB)) ? ws_size / 4 - 2 * NB : 0;
    int Tc = T_DIM;
    while (Tc > 1 && (size_t)Tc * NB > avail_f) Tc >>= 1;
    const int nc = T_DIM / Tc;
    for (int c = 0; c < nc; ++c) {
        const int M = Tc * B_DIM;
        dim3 grid(M / TM, F_DIM / TN);
        gemm_kernel<<<grid, 256, 0, stream>>>(S + (size_t)c * Tc * NB, W, xs);
        scan_kernel<<<NB / 256, 256, 0, stream>>>(xs, vi, out, Tc,
                                                  (c == 0) ? 1 : 0,
                                                  (c == nc - 1) ? 1 : 0);
    }
}